// Round 1
// 238.400 us; speedup vs baseline: 1.0794x; 1.0794x over previous
//
#include <hip/hip_runtime.h>
#include <hip/hip_fp16.h>
#include <hip/hip_bf16.h>

#define B 8
#define H 2048
#define D 2
#define HH (H*H)
#define TILE 64
#define NT (H/TILE)          /* 32 */
#define NPAIR (NT*(NT+1)/2)  /* 528 upper-tri tile-pairs */
#define INV2PI 0.15915494309189535f
#define INVH (1.0f/2048.0f)

// v_sin/v_cos take revolutions; |args| << 256 rev -> safe.
__device__ __forceinline__ float fsin(float x) { return __builtin_amdgcn_sinf(x * INV2PI); }
__device__ __forceinline__ float fcos(float x) { return __builtin_amdgcn_cosf(x * INV2PI); }

__device__ __forceinline__ void pair_decode(int tp, int& ti, int& tj) {
    ti = 0;
    while (tp >= NT - ti) { tp -= NT - ti; ti++; }
    tj = ti + tp;
}

// ---------------- primary path ----------------
// k_stage: grid (NPAIR, B), 256 thr. Per (b, pair): compute al = relu(.5(A+A^T))+1e-6
// once per unordered pair, store packed bf16; per-block min/max partials.
// b==0 blocks also build packed f16 dm = tanh(dl-dl^T) tiles; b==1/pair<64 do
// the elementwise prework (sincos table + out base).
__global__ __launch_bounds__(256) void k_stage(
    const float* __restrict__ A, const float* __restrict__ dl,
    const float* __restrict__ theta, const float* __restrict__ gamma,
    const float* __restrict__ omega, const float* __restrict__ kappa,
    float* __restrict__ out, float4* __restrict__ sc,
    __hip_bfloat16* __restrict__ alw, __half* __restrict__ dmw,
    float* __restrict__ pmn, float* __restrict__ pmx) {
    int pair = blockIdx.x, b = blockIdx.y;
    int ti, tj; pair_decode(pair, ti, tj);
    int t = threadIdx.x, c = t & 63, r0 = t >> 6;

    __shared__ float l2[TILE][TILE + 1];
    const float* Ab = A + (size_t)b * HH;

    float v[16];
    #pragma unroll
    for (int k = 0; k < 16; k++)
        v[k] = Ab[(size_t)(tj * TILE + r0 + 4 * k) * H + ti * TILE + c];
    #pragma unroll
    for (int k = 0; k < 16; k++) l2[r0 + 4 * k][c] = v[k];
    __syncthreads();
    #pragma unroll
    for (int k = 0; k < 16; k++)
        v[k] = Ab[(size_t)(ti * TILE + r0 + 4 * k) * H + tj * TILE + c];

    __hip_bfloat16* alp = alw + ((size_t)b * NPAIR + pair) * (TILE * TILE);
    float mn = 3.0e38f, mx = 0.f;
    #pragma unroll
    for (int k = 0; k < 16; k++) {
        int il = r0 + 4 * k;
        float al = fmaxf(0.5f * (v[k] + l2[c][il]), 0.f) + 1e-6f;
        mn = fminf(mn, al); mx = fmaxf(mx, al);
        alp[il * TILE + c] = __float2bfloat16(al);   // coalesced ushort stores
    }
    #pragma unroll
    for (int off = 32; off; off >>= 1) {
        mn = fminf(mn, __shfl_xor(mn, off));
        mx = fmaxf(mx, __shfl_xor(mx, off));
    }
    __shared__ float smn[4], smx[4];
    int wv = t >> 6, ln = t & 63;
    if (ln == 0) { smn[wv] = mn; smx[wv] = mx; }
    __syncthreads();
    if (t == 0) {
        for (int i = 1; i < 4; i++) { mn = fminf(mn, smn[i]); mx = fmaxf(mx, smx[i]); }
        pmn[b * NPAIR + pair] = mn;
        pmx[b * NPAIR + pair] = mx;
    }

    if (b == 0) {   // dm tiles (b-independent): reuse LDS after barrier
        __syncthreads();
        float w2[16];
        #pragma unroll
        for (int k = 0; k < 16; k++)
            w2[k] = dl[(size_t)(tj * TILE + r0 + 4 * k) * H + ti * TILE + c];
        #pragma unroll
        for (int k = 0; k < 16; k++) l2[r0 + 4 * k][c] = w2[k];
        __syncthreads();
        #pragma unroll
        for (int k = 0; k < 16; k++)
            w2[k] = dl[(size_t)(ti * TILE + r0 + 4 * k) * H + tj * TILE + c];
        __half* dmp = dmw + (size_t)pair * (TILE * TILE);
        #pragma unroll
        for (int k = 0; k < 16; k++) {
            int il = r0 + 4 * k;
            float x = w2[k] - l2[c][il];
            float x2 = x * x;  // |x| <= ~0.08 -> 3-term odd poly exact to ~1e-9
            float dmv = x * fmaf(x2, fmaf(x2, 0.13333334f, -0.33333334f), 1.0f);
            dmp[il * TILE + c] = __float2half(dmv);
        }
    }

    if (b == 1 && pair < (B * H) / 256) {   // elementwise prework
        int g = pair * 256 + t;             // g = bb*H + i
        int i = g & (H - 1);
        float th0 = theta[(size_t)g * 2 + 0];
        float th1 = theta[(size_t)g * 2 + 1];
        sc[g] = make_float4(fsin(th0), fcos(th0), fsin(th1), fcos(th1));
        float gm = gamma[g];
        out[(size_t)g * 2 + 0] = th0 + omega[i * 2 + 0] + kappa[i * 2 + 0] * fsin(gm - th0);
        out[(size_t)g * 2 + 1] = th1 + omega[i * 2 + 1] + kappa[i * 2 + 1] * fsin(gm - th1);
    }
}

// One block per batch: reduce NPAIR partials -> mmf[b*2]={min}, [b*2+1]={max}.
__global__ __launch_bounds__(256) void k_mmred(const float* __restrict__ pmn,
                                               const float* __restrict__ pmx,
                                               float* __restrict__ mmf) {
    int b = blockIdx.x, t = threadIdx.x;
    float mn = 3.0e38f, mx = 0.f;
    for (int k = t; k < NPAIR; k += 256) {
        mn = fminf(mn, pmn[b * NPAIR + k]);
        mx = fmaxf(mx, pmx[b * NPAIR + k]);
    }
    #pragma unroll
    for (int off = 32; off; off >>= 1) {
        mn = fminf(mn, __shfl_xor(mn, off));
        mx = fmaxf(mx, __shfl_xor(mx, off));
    }
    __shared__ float smn[4], smx[4];
    int wv = t >> 6, ln = t & 63;
    if (ln == 0) { smn[wv] = mn; smx[wv] = mx; }
    __syncthreads();
    if (t == 0) {
        for (int i = 1; i < 4; i++) { mn = fminf(mn, smn[i]); mx = fmaxf(mx, smx[i]); }
        mmf[b * 2 + 0] = mn;
        mmf[b * 2 + 1] = mx;
    }
}

// k_main: grid (NPAIR, B), 256 thr = 4 waves. Upper-tri pairs only; contribution
// of (i,j) to j is the NEGATIVE of its contribution to i (al symmetric, alpha
// antisymmetric), so each unordered pair is computed once and +- scattered.
// Reduction restructure (this round): no per-iteration butterflies -- stash row
// values to LDS (1 ds_write2 vs 12 swizzles + 12 adds), reduce once after the
// loop. No atomics -- each (b,i,d) gets exactly one partial per slot s in [0,32):
//   row-part of pair (ti,tj) -> buf[b][tj][i in ti][d]
//   col-part of pair (ti,tj) -> buf[b][ti][j in tj][d]   (skipped on diagonal)
// which covers every slot exactly once (s<ti via col of (s,ti), s>ti via row of
// (ti,s), s==ti via diag row). k_fin folds the 32 slots into out.
__global__ __launch_bounds__(256) void k_main(
    const __hip_bfloat16* __restrict__ alw, const __half* __restrict__ dmw,
    const float4* __restrict__ sc, const float* __restrict__ mmf,
    float* __restrict__ buf) {
    int pair = blockIdx.x, b = blockIdx.y;
    int ti, tj; pair_decode(pair, ti, tj);
    bool diag = (ti == tj);
    int t = threadIdx.x, w = t >> 6, ln = t & 63;

    __shared__ float4 ldssc[TILE];     // i-tile sincos
    __shared__ float rowv[128][68];    // [w*32 + 2k + d][ln]; stride 68 -> uniform banks
    __shared__ float2 colv[4][TILE];   // per-wave col partials

    float amin = mmf[b * 2 + 0];
    float amax = mmf[b * 2 + 1];
    float cmin = 1.0f / amax, cmax = 1.0f / amin;
    float invr = 1.0f / (cmax - cmin + 1e-6f);
    float ncb = cmin * invr;           // nc = cost*invr - ncb

    const float4* scb = sc + (size_t)b * H;
    if (t < TILE) ldssc[t] = scb[ti * TILE + t];

    int j = tj * TILE + ln;
    float4 scj = scb[j];
    float sj0 = scj.x, cj0 = scj.y, sj1 = scj.z, cj1 = scj.w;
    __syncthreads();

    const __hip_bfloat16* alp = alw + ((size_t)b * NPAIR + pair) * (TILE * TILE);
    const __half* dmp = dmw + (size_t)pair * (TILE * TILE);

    float accj0 = 0.f, accj1 = 0.f;    // col (j) accumulators, per lane

    #pragma unroll
    for (int k = 0; k < 16; k++) {
        int il = w * 16 + k;
        float4 sciv = ldssc[il];       // wave-uniform broadcast
        float si0 = sciv.x, ci0 = sciv.y, si1 = sciv.z, ci1 = sciv.w;

        float al = __bfloat162float(alp[il * TILE + ln]);
        float dmv = __half2float(dmp[il * TILE + ln]);
        float cost = __builtin_amdgcn_rcpf(al);
        float nc = fmaf(cost, invr, -ncb);
        float alpha = dmv * nc;
        float a2 = alpha * alpha;
        float sa = alpha * fmaf(a2, -0.16666667f, 1.0f);
        float ca = fmaf(a2, -0.5f, 1.0f);
        float sd0 = fmaf(sj0, ci0, -cj0 * si0);   // sin(th_j - th_i)
        float cd0 = fmaf(cj0, ci0,  sj0 * si0);   // cos(th_j - th_i)
        float c0 = al * fmaf(sd0, ca, -cd0 * sa); // al*sin(th_j-th_i-alpha)
        float sd1 = fmaf(sj1, ci1, -cj1 * si1);
        float cd1 = fmaf(cj1, ci1,  sj1 * si1);
        float c1 = al * fmaf(sd1, ca, -cd1 * sa);

        accj0 -= c0;                   // scatter to j with negative sign
        accj1 -= c1;

        rowv[w * 32 + 2 * k + 0][ln] = c0;   // stash; reduce after loop
        rowv[w * 32 + 2 * k + 1][ln] = c1;
    }

    colv[w][ln] = make_float2(accj0, accj1);
    __syncthreads();

    if (t < 128) {                     // row (i) sums: one (il,d) per thread
        const float* p = &rowv[t][0];
        float s = 0.f;
        #pragma unroll
        for (int q = 0; q < 64; q += 4) {
            float4 v4 = *(const float4*)(p + q);   // 16x ds_read_b128
            s += (v4.x + v4.y) + (v4.z + v4.w);
        }
        int il = (t >> 5) * 16 + ((t >> 1) & 15);
        int d = t & 1;
        buf[(((size_t)b * NT + tj) * H + ti * TILE + il) * 2 + d] = s * INVH;
    } else if (!diag) {                // col (j) sums: 2 waves, 128 values
        int u = t - 128;
        int jl = u >> 1, d = u & 1;
        const float* cvf = (const float*)colv;
        int off = jl * 2 + d;
        float cs = cvf[off] + cvf[128 + off] + cvf[256 + off] + cvf[384 + off];
        buf[(((size_t)b * NT + ti) * H + tj * TILE + jl) * 2 + d] = cs * INVH;
    }
}

// Fold the 32 disjoint slot-partials into out (out already holds the
// elementwise part written by k_stage). B*H*2/256 = 128 blocks.
__global__ __launch_bounds__(256) void k_fin(const float* __restrict__ buf,
                                             float* __restrict__ out) {
    int idx = blockIdx.x * 256 + threadIdx.x;   // over B*H*2 = 32768
    int b = idx >> 12;                          // / (H*2)
    int rem = idx & 4095;
    const float* p = buf + (size_t)b * NT * (H * 2) + rem;
    float s = 0.f;
    #pragma unroll
    for (int q = 0; q < NT; q++) s += p[(size_t)q * (H * 2)];
    out[idx] += s;
}

// ---------------- fallback path (known-good; used if ws too small) ----------

__global__ void k_init_fb(unsigned int* mm) {
    int t = threadIdx.x;
    if (t < B * 2) mm[t] = (t & 1) ? 0u : 0x7f800000u;
}

__global__ __launch_bounds__(256) void k_minmax_fb(const float* __restrict__ A,
                                                   unsigned int* __restrict__ mm) {
    int b = blockIdx.y;
    int tp = blockIdx.x;
    int ti, tj; pair_decode(tp, ti, tj);

    __shared__ float l2[TILE][TILE + 1];
    const float* Ab = A + (size_t)b * HH;
    int t = threadIdx.x;
    int c = t & 63, r0 = t >> 6;

    #pragma unroll
    for (int k = 0; k < 16; k++)
        l2[r0 + 4 * k][c] = Ab[(size_t)(tj * TILE + r0 + 4 * k) * H + ti * TILE + c];
    __syncthreads();

    float mn = 3.0e38f, mx = 0.f;
    #pragma unroll
    for (int k = 0; k < 16; k++) {
        int il = r0 + 4 * k;
        float aij = Ab[(size_t)(ti * TILE + il) * H + tj * TILE + c];
        float v = fmaxf(0.5f * (aij + l2[c][il]), 0.f) + 1e-6f;
        mn = fminf(mn, v); mx = fmaxf(mx, v);
    }
    #pragma unroll
    for (int off = 32; off; off >>= 1) {
        mn = fminf(mn, __shfl_xor(mn, off));
        mx = fmaxf(mx, __shfl_xor(mx, off));
    }
    __shared__ float smn[4], smx[4];
    int wv = t >> 6, ln = t & 63;
    if (ln == 0) { smn[wv] = mn; smx[wv] = mx; }
    __syncthreads();
    if (t == 0) {
        for (int i = 1; i < 4; i++) { mn = fminf(mn, smn[i]); mx = fmaxf(mx, smx[i]); }
        atomicMin(&mm[b * 2 + 0], __float_as_uint(mn));
        atomicMax(&mm[b * 2 + 1], __float_as_uint(mx));
    }
}

__global__ __launch_bounds__(1024) void k_main_fb(
    const float* __restrict__ theta, const float* __restrict__ gamma,
    const float* __restrict__ A, const float* __restrict__ omega,
    const float* __restrict__ kappa, const float* __restrict__ dl,
    const unsigned int* __restrict__ mm, float* __restrict__ out) {
    int b = blockIdx.y;
    int i0 = blockIdx.x * TILE;
    int t = threadIdx.x;
    int w = t >> 6, ln = t & 63;

    __shared__ float aT[TILE][TILE + 1];
    __shared__ float dT[TILE][TILE + 1];
    __shared__ float thI[4][TILE];
    __shared__ float thJ[4][TILE];

    float amin = __uint_as_float(mm[b * 2 + 0]);
    float amax = __uint_as_float(mm[b * 2 + 1]);
    float cmin = 1.0f / amax, cmax = 1.0f / amin;
    float invr = 1.0f / (cmax - cmin + 1e-6f);

    if (t < 128) {
        int il = t & 63, d = t >> 6;
        float th = theta[(size_t)(b * H + i0 + il) * D + d];
        thI[d * 2 + 0][il] = fsin(th);
        thI[d * 2 + 1][il] = fcos(th);
    }
    __syncthreads();

    float si[4][2], ci[4][2];
    #pragma unroll
    for (int k = 0; k < 4; k++)
        #pragma unroll
        for (int d = 0; d < 2; d++) {
            si[k][d] = thI[d * 2 + 0][w * 4 + k];
            ci[k][d] = thI[d * 2 + 1][w * 4 + k];
        }

    float acc[4][2] = {};
    const float* Ab = A + (size_t)b * HH;

    for (int jt = 0; jt < NT; jt++) {
        int j0 = jt * TILE;
        __syncthreads();
        #pragma unroll
        for (int k = 0; k < 4; k++) {
            int r = w * 4 + k;
            aT[r][ln] = Ab[(size_t)(j0 + r) * H + i0 + ln];
            dT[r][ln] = dl[(size_t)(j0 + r) * H + i0 + ln];
        }
        if (t < 128) {
            int jl = t & 63, d = t >> 6;
            float th = theta[(size_t)(b * H + j0 + jl) * D + d];
            thJ[d * 2 + 0][jl] = fsin(th);
            thJ[d * 2 + 1][jl] = fcos(th);
        }
        __syncthreads();

        float sj0 = thJ[0][ln], cj0 = thJ[1][ln];
        float sj1 = thJ[2][ln], cj1 = thJ[3][ln];
        const float* arow = Ab + (size_t)(i0 + w * 4) * H + j0 + ln;
        const float* drow = dl + (size_t)(i0 + w * 4) * H + j0 + ln;
        #pragma unroll
        for (int k = 0; k < 4; k++) {
            float aij = arow[(size_t)k * H];
            float dij = drow[(size_t)k * H];
            float aji = aT[ln][w * 4 + k];
            float dji = dT[ln][w * 4 + k];
            float al = fmaxf(0.5f * (aij + aji), 0.f) + 1e-6f;
            float cost = __builtin_amdgcn_rcpf(al);
            float nc = (cost - cmin) * invr;
            float x = dij - dji;
            float x2 = x * x;
            float dmv = x * fmaf(x2, fmaf(x2, 0.13333334f, -0.33333334f), 1.0f);
            float alpha = dmv * nc;
            float sa = fsin(alpha), ca = fcos(alpha);
            {
                float sd = sj0 * ci[k][0] - cj0 * si[k][0];
                float cd = cj0 * ci[k][0] + sj0 * si[k][0];
                acc[k][0] = fmaf(al, sd * ca - cd * sa, acc[k][0]);
            }
            {
                float sd = sj1 * ci[k][1] - cj1 * si[k][1];
                float cd = cj1 * ci[k][1] + sj1 * si[k][1];
                acc[k][1] = fmaf(al, sd * ca - cd * sa, acc[k][1]);
            }
        }
    }

    #pragma unroll
    for (int k = 0; k < 4; k++)
        #pragma unroll
        for (int d = 0; d < 2; d++)
            #pragma unroll
            for (int off = 32; off; off >>= 1)
                acc[k][d] += __shfl_xor(acc[k][d], off);

    if (ln < 8) {
        int k = ln >> 1, d = ln & 1;
        int i = i0 + w * 4 + k;
        size_t idx = (size_t)(b * H + i) * D + d;
        float chosen = __shfl(acc[k][d], k * 2 + d);
        float th = theta[idx];
        float drv = kappa[i * D + d] * fsin(gamma[b * H + i] - th);
        out[idx] = th + (omega[i * D + d] + (1.0f / H) * chosen + drv);
    }
}

// ---------------- launch ----------------

extern "C" void kernel_launch(void* const* d_in, const int* in_sizes, int n_in,
                              void* d_out, int out_size, void* d_ws, size_t ws_size,
                              hipStream_t stream) {
    const float* theta = (const float*)d_in[0];
    const float* gamma = (const float*)d_in[1];
    const float* A     = (const float*)d_in[2];
    const float* omega = (const float*)d_in[3];
    const float* kappa = (const float*)d_in[4];
    const float* dl    = (const float*)d_in[5];
    float* out = (float*)d_out;

    // ws layout
    float* mmf = (float*)d_ws;                                        // 64 B
    float* pmn = (float*)((char*)d_ws + 1024);                        // 16.9 KB
    float* pmx = pmn + B * NPAIR;
    float4* sc = (float4*)((char*)d_ws + 65536);                      // 256 KB
    size_t off_dmw = 65536 + 262144;
    __half* dmw = (__half*)((char*)d_ws + off_dmw);                   // 4.3 MB
    size_t off_alw = off_dmw + (size_t)NPAIR * TILE * TILE * 2;
    __hip_bfloat16* alw = (__hip_bfloat16*)((char*)d_ws + off_alw);   // 34.6 MB
    size_t off_buf = off_alw + (size_t)B * NPAIR * TILE * TILE * 2;
    float* buf = (float*)((char*)d_ws + off_buf);                     // 4.2 MB
    size_t need = off_buf + (size_t)B * NT * H * D * 4;

    if (ws_size >= need) {
        hipLaunchKernelGGL(k_stage, dim3(NPAIR, B), dim3(256), 0, stream,
                           A, dl, theta, gamma, omega, kappa, out, sc, alw, dmw, pmn, pmx);
        hipLaunchKernelGGL(k_mmred, dim3(B), dim3(256), 0, stream, pmn, pmx, mmf);
        hipLaunchKernelGGL(k_main, dim3(NPAIR, B), dim3(256), 0, stream,
                           alw, dmw, sc, mmf, buf);
        hipLaunchKernelGGL(k_fin, dim3((B * H * D) / 256), dim3(256), 0, stream,
                           buf, out);
    } else {
        unsigned int* mm = (unsigned int*)d_ws;
        hipLaunchKernelGGL(k_init_fb, dim3(1), dim3(64), 0, stream, mm);
        hipLaunchKernelGGL(k_minmax_fb, dim3(NPAIR, B), dim3(256), 0, stream, A, mm);
        hipLaunchKernelGGL(k_main_fb, dim3(NT, B), dim3(1024), 0, stream,
                           theta, gamma, A, omega, kappa, dl, mm, out);
    }
}